// Round 5
// baseline (527.809 us; speedup 1.0000x reference)
//
#include <hip/hip_runtime.h>
#include <hip/hip_fp16.h>

typedef _Float16 f16;
typedef __attribute__((ext_vector_type(8))) _Float16 f16x8;
typedef __attribute__((ext_vector_type(4))) float f32x4;

#define NPTS 8192
#define DIM  1024
#define HL2E 0.721347520444482f   // log2(e)/2
#define S2SHIFT 50.0f             // store exp((s-50)/2) in f16
#define BUF3 12288                // f16 elems per 256x128 buffer (A 8192 + B 4096) = 24 KB

// async global->LDS, 16B per lane; lds base must be wave-uniform
__device__ __forceinline__ void glds16(const void* g, void* l) {
  __builtin_amdgcn_global_load_lds(
      (const __attribute__((address_space(1))) void*)g,
      (__attribute__((address_space(3))) void*)l, 16, 0, 0);
}

// LDS chunk swizzle (proven: conflicts 1.7e7 -> 0): data chunk kc of row ro
// lives at slot kc ^ ((ro>>1)&3); glds stage lanes fetch global chunk
// (t&3)^((t>>3)&3); frag reads use per-lane base with the same XOR.
//
// 256x128 3-buffer template (this round): tile M=256 N=128 BK=32, 512 thr
// (8 waves 4Mx2N, per-wave 64x64 output, acc[4][4] = 64 VGPR), 3 LDS buffers
// (72 KB) -> 2 blocks/CU (the R4 128KB kernel was 1 block/CU, Occupancy 21%,
// MfmaUtil 45%: all waves share one barrier shadow). Stage 2 K-tiles ahead;
// ONE raw s_barrier + ONE counted vmcnt per tile (never 0). Race safety:
// stage target buf (kt+2)%3 == buf of kt-1, whose reads completed before
// barrier(kt-1) which precedes the stage issue; waiting vmcnt(#issues/tile)
// at barrier(kt) retires tile kt+1's loads => resident for all waves.

// ---------- small helpers ----------
__global__ void cvt_f32_f16(const float* __restrict__ src, f16* __restrict__ dst, int n) {
  int i = (blockIdx.x * 256 + threadIdx.x) * 8;
  if (i >= n) return;
  const float4* s = (const float4*)(src + i);
  float4 a = s[0], b = s[1];
  f16x8 o;
  o[0] = (f16)a.x; o[1] = (f16)a.y; o[2] = (f16)a.z; o[3] = (f16)a.w;
  o[4] = (f16)b.x; o[5] = (f16)b.y; o[6] = (f16)b.z; o[7] = (f16)b.w;
  *(f16x8*)(dst + i) = o;
}

__global__ void zero_f32(float* __restrict__ p, int n) {
  int i = blockIdx.x * 256 + threadIdx.x;
  if (i < n) p[i] = 0.f;
}

// colsum (= sum of e^2) -> ics2 = cs^-1/2 (for v), ics4 = cs^-1/4 (for P frags)
__global__ void mk_scales(const float* __restrict__ colsum,
                          f16* __restrict__ ics2, f16* __restrict__ ics4) {
  int j = blockIdx.x * 256 + threadIdx.x;
  float r2 = rsqrtf(fmaxf(colsum[j], 1e-20f));
  ics2[j] = (f16)r2;
  ics4[j] = (f16)sqrtf(r2);
}

// vt[n][j] *= ics2[j]  (in place, 8-wide packed)
__global__ void vscale(f16* __restrict__ vt, const f16* __restrict__ ics2) {
  long i = ((long)blockIdx.x * 256 + threadIdx.x) * 8;
  f16x8 v = *(f16x8*)(vt + i);
  f16x8 s = *(const f16x8*)(ics2 + (i & (NPTS - 1)));
  *(f16x8*)(vt + i) = v * s;
}

// out = p + part0 + part1  (PV split-K combine + residual)
__global__ void reduce_out(const float* __restrict__ p,
                           const float* __restrict__ pa,
                           const float* __restrict__ pb,
                           float* __restrict__ out) {
  long i = ((long)blockIdx.x * 256 + threadIdx.x) * 4;
  float4 a = *(const float4*)(p + i);
  float4 b = *(const float4*)(pa + i);
  float4 c = *(const float4*)(pb + i);
  a.x += b.x + c.x; a.y += b.y + c.y; a.z += b.z + c.z; a.w += b.w + c.w;
  *(float4*)(out + i) = a;
}

// ---------- fused projections: q = p@Wh^T+bh, k = r@Wl^T+bl, vt = (p@Wg^T+bg)^T ----------
// 256x128 3-buf template. Grid 768 = 3 sub x 8 bj(XCD) x 32 bi. Each XCD's
// W-panel (128x1024 = 256 KB) reused by its 32 bi-blocks via L2.
__global__ __launch_bounds__(512, 4)
void proj_fused(const f16* __restrict__ p_h, const f16* __restrict__ r_h,
                const f16* __restrict__ Wh, const f16* __restrict__ Wl,
                const f16* __restrict__ Wg,
                const float* __restrict__ bh, const float* __restrict__ bl,
                const float* __restrict__ bg,
                f16* __restrict__ q_h, f16* __restrict__ k_h,
                f16* __restrict__ vt_h) {
  __shared__ f16 smem[3 * BUF3];
  const int b = blockIdx.x;
  const int sub = b >> 8;
  const int rest = b & 255;
  const long bj = (long)(rest & 7) * 128;   // XCD-pinned W-panel
  const long bi = (long)(rest >> 3) * 256;
  const f16* A = (sub == 1) ? r_h : p_h;
  const f16* B = (sub == 0) ? Wh : (sub == 1) ? Wl : Wg;
  const float* bias = (sub == 0) ? bh : (sub == 1) ? bl : bg;

  const int t = threadIdx.x;
  const int w = t >> 6, l = t & 63;
  const int wm = (w >> 1) * 64, wn = (w & 1) * 64;   // 4Mx2N waves, 64x64 each
  const int lr = l & 15;
  const int fbase = lr * 32 + (((l >> 4) ^ ((lr >> 1) & 3)) * 8);
  const int sro = t >> 2;
  const int scol = ((t & 3) ^ ((t >> 3) & 3)) * 8;
  const f16* gAs = A + (bi + sro) * (long)DIM + scol;
  const f16* gBs = B + (bj + sro) * (long)DIM + scol;
  const int ldst = w * 512;

#pragma unroll
  for (int tl = 0; tl < 2; ++tl) {
    f16* d = smem + tl * BUF3;
    glds16(gAs + tl * 32,              d + ldst);
    glds16(gAs + tl * 32 + 128l * DIM, d + 4096 + ldst);
    glds16(gBs + tl * 32,              d + 8192 + ldst);
  }
  asm volatile("s_waitcnt vmcnt(3)" ::: "memory");
  __builtin_amdgcn_s_barrier();
  asm volatile("" ::: "memory");

  f32x4 acc[4][4] = {};
  const int nk = DIM / 32;   // 32
  int cOff = 0, tOff = 2 * BUF3;
  for (int kt = 0; kt < nk; ++kt) {
    const f16* sa = smem + cOff;
    f16* d = smem + tOff;
    const int ks = (kt + 2 < nk) ? (kt + 2) : nk - 1;
    f16x8 af[4], bf[4];
#pragma unroll
    for (int mt = 0; mt < 4; ++mt)
      af[mt] = *(const f16x8*)(sa + (wm + mt * 16) * 32 + fbase);
#pragma unroll
    for (int nt = 0; nt < 4; ++nt)
      bf[nt] = *(const f16x8*)(sa + 8192 + (wn + nt * 16) * 32 + fbase);
    glds16(gAs + ks * 32,              d + ldst);
    glds16(gAs + ks * 32 + 128l * DIM, d + 4096 + ldst);
    glds16(gBs + ks * 32,              d + 8192 + ldst);
#pragma unroll
    for (int mt = 0; mt < 4; ++mt)
#pragma unroll
      for (int nt = 0; nt < 4; ++nt)
        acc[mt][nt] = __builtin_amdgcn_mfma_f32_16x16x32_f16(af[mt], bf[nt], acc[mt][nt], 0, 0, 0);
    asm volatile("s_waitcnt vmcnt(3)" ::: "memory");
    __builtin_amdgcn_s_barrier();
    asm volatile("" ::: "memory");
    cOff += BUF3; if (cOff == 3 * BUF3) cOff = 0;
    tOff += BUF3; if (tOff == 3 * BUF3) tOff = 0;
  }

  const int rbase = (l >> 4) * 4;
  f16* C = (sub == 0) ? q_h : (sub == 1) ? k_h : vt_h;
#pragma unroll
  for (int nt = 0; nt < 4; ++nt) {
    const long col = bj + wn + nt * 16 + lr;
    const float bb = bias[col];
#pragma unroll
    for (int mt = 0; mt < 4; ++mt) {
      const long row0 = bi + wm + mt * 16 + rbase;
      if (sub < 2) {
#pragma unroll
        for (int g = 0; g < 4; ++g)
          C[(row0 + g) * DIM + col] = (f16)(acc[mt][nt][g] + bb);
      } else {
        union { unsigned long long u; f16 h[4]; } pk;
#pragma unroll
        for (int g = 0; g < 4; ++g) pk.h[g] = (f16)(acc[mt][nt][g] + bb);
        *(unsigned long long*)(C + col * (long)NPTS + row0) = pk.u;
      }
    }
  }
}

// ---------- QK^T: S = exp((s-50)/2) f16, fused column sum of squares ----------
// 256x128 3-buf template. Grid 2048 = 8 sx x (32 bi x 8 bjq); XCD sx owns
// bj-panels sx*8..sx*8+7 (8 x 128 k-rows x 1024 = 2 MB, L2-resident).
__global__ __launch_bounds__(512, 4)
void gemm_qk(const f16* __restrict__ A, const f16* __restrict__ B,
             f16* __restrict__ S, float* __restrict__ colsum) {
  __shared__ f16 smem[3 * BUF3];
  const int b = blockIdx.x;
  const int sx = b & 7;
  const int j = b >> 3;                       // 0..255
  const long bi = (long)(j >> 3) * 256;       // 32 values
  const long bj = (long)(sx * 8 + (j & 7)) * 128;  // 64 values

  const int t = threadIdx.x;
  const int w = t >> 6, l = t & 63;
  const int wm = (w >> 1) * 64, wn = (w & 1) * 64;
  const int lr = l & 15;
  const int fbase = lr * 32 + (((l >> 4) ^ ((lr >> 1) & 3)) * 8);
  const int sro = t >> 2;
  const int scol = ((t & 3) ^ ((t >> 3) & 3)) * 8;
  const f16* gAs = A + (bi + sro) * (long)DIM + scol;
  const f16* gBs = B + (bj + sro) * (long)DIM + scol;
  const int ldst = w * 512;

#pragma unroll
  for (int tl = 0; tl < 2; ++tl) {
    f16* d = smem + tl * BUF3;
    glds16(gAs + tl * 32,              d + ldst);
    glds16(gAs + tl * 32 + 128l * DIM, d + 4096 + ldst);
    glds16(gBs + tl * 32,              d + 8192 + ldst);
  }
  asm volatile("s_waitcnt vmcnt(3)" ::: "memory");
  __builtin_amdgcn_s_barrier();
  asm volatile("" ::: "memory");

  f32x4 acc[4][4] = {};
  const int nk = DIM / 32;
  int cOff = 0, tOff = 2 * BUF3;
  for (int kt = 0; kt < nk; ++kt) {
    const f16* sa = smem + cOff;
    f16* d = smem + tOff;
    const int ks = (kt + 2 < nk) ? (kt + 2) : nk - 1;
    f16x8 af[4], bf[4];
#pragma unroll
    for (int mt = 0; mt < 4; ++mt)
      af[mt] = *(const f16x8*)(sa + (wm + mt * 16) * 32 + fbase);
#pragma unroll
    for (int nt = 0; nt < 4; ++nt)
      bf[nt] = *(const f16x8*)(sa + 8192 + (wn + nt * 16) * 32 + fbase);
    glds16(gAs + ks * 32,              d + ldst);
    glds16(gAs + ks * 32 + 128l * DIM, d + 4096 + ldst);
    glds16(gBs + ks * 32,              d + 8192 + ldst);
#pragma unroll
    for (int mt = 0; mt < 4; ++mt)
#pragma unroll
      for (int nt = 0; nt < 4; ++nt)
        acc[mt][nt] = __builtin_amdgcn_mfma_f32_16x16x32_f16(af[mt], bf[nt], acc[mt][nt], 0, 0, 0);
    asm volatile("s_waitcnt vmcnt(3)" ::: "memory");
    __builtin_amdgcn_s_barrier();
    asm volatile("" ::: "memory");
    cOff += BUF3; if (cOff == 3 * BUF3) cOff = 0;
    tOff += BUF3; if (tOff == 3 * BUF3) tOff = 0;
  }

  // epilogue: e = exp((s-50)/2) clamped to 240 (f16-normal; sqrt-split keeps
  // all stored factors away from subnormals — R3 lesson). colsum sums ef^2 of
  // the SAME f16 values PV reads. nt innermost: 64B-line-grouped stores.
  const int rbase = (l >> 4) * 4;
  float csum[4] = {0.f, 0.f, 0.f, 0.f};
#pragma unroll
  for (int mt = 0; mt < 4; ++mt) {
#pragma unroll
    for (int g = 0; g < 4; ++g) {
      const long row = bi + wm + mt * 16 + rbase + g;
      f16* Srow = S + row * NPTS + bj + wn + lr;
#pragma unroll
      for (int nt = 0; nt < 4; ++nt) {
        float e = exp2f((acc[mt][nt][g] - S2SHIFT) * HL2E);
        e = fminf(e, 240.f);              // e^2 <= 57600 < f16 max
        f16 eh = (f16)e;
        Srow[nt * 16] = eh;
        float ef = (float)eh;
        csum[nt] += ef * ef;
      }
    }
  }
#pragma unroll
  for (int nt = 0; nt < 4; ++nt) {
    float cs = csum[nt];
    cs += __shfl_xor(cs, 16);
    cs += __shfl_xor(cs, 32);
    if (l < 16) atomicAdd(colsum + (bj + wn + nt * 16 + lr), cs);
  }
}

// ---------- PV split-K x2: part[s] = ((S.ics4)^2) @ v~ ----------
// 256x128 3-buf template + in-register P transform: P = (e*ics4)^2, multiply
// FIRST then square (every intermediate f16-normal — R3 lesson). ics4 chunk
// (l>>4)*8 shared by all 4 M-frags; 2-deep shift register ic0<-ic1<-new
// (named regs, no runtime indexing). 4 vmem issues/tile (1 ic + 3 glds) ->
// counted wait vmcnt(4) retires tile kt+1's batch. Grid 512 = 8 sx x 64;
// XCD sx owns (bj,split) pairs {sx*2, sx*2+1}: 2 x 1 MB v~-panels L2-resident,
// each reused by 32 bi-blocks.
__global__ __launch_bounds__(512, 4)
void gemm_pv(const f16* __restrict__ Sm, const f16* __restrict__ vt,
             const f16* __restrict__ ics4,
             float* __restrict__ part0, float* __restrict__ part1) {
  __shared__ f16 smem[3 * BUF3];
  const int b = blockIdx.x;         // 0..511
  const int sx = b & 7;
  const int q = b >> 3;             // 0..63
  const int pp = sx * 2 + (q & 1);  // (bj,split) 0..15
  const long bj = (long)(pp & 7) * 128;
  const int split = pp >> 3;
  const long bi = (long)(q >> 1) * 256;
  const long koff = (long)split * (NPTS / 2);

  const int t = threadIdx.x;
  const int w = t >> 6, l = t & 63;
  const int wm = (w >> 1) * 64, wn = (w & 1) * 64;
  const int lr = l & 15;
  const int fbase = lr * 32 + (((l >> 4) ^ ((lr >> 1) & 3)) * 8);
  const int sro = t >> 2;
  const int scol = ((t & 3) ^ ((t >> 3) & 3)) * 8;
  const f16* gAs = Sm + (bi + sro) * (long)NPTS + koff + scol;
  const f16* gBs = vt + (bj + sro) * (long)NPTS + koff + scol;
  const f16* gic = ics4 + koff + (l >> 4) * 8;
  const int ldst = w * 512;

  const int nk = (NPTS / 2) / 32;   // 128

  f16x8 ic0 = *(const f16x8*)(gic);        // for kt=0
  f16x8 ic1 = *(const f16x8*)(gic + 32);   // for kt=1
#pragma unroll
  for (int tl = 0; tl < 2; ++tl) {
    f16* d = smem + tl * BUF3;
    glds16(gAs + tl * 32,               d + ldst);
    glds16(gAs + tl * 32 + 128l * NPTS, d + 4096 + ldst);
    glds16(gBs + tl * 32,               d + 8192 + ldst);
  }
  asm volatile("s_waitcnt vmcnt(3)" ::: "memory");  // ic0/ic1 + tile0 retired
  __builtin_amdgcn_s_barrier();
  asm volatile("" ::: "memory");

  f32x4 acc[4][4] = {};
  int cOff = 0, tOff = 2 * BUF3;
  for (int kt = 0; kt < nk; ++kt) {
    const f16* sa = smem + cOff;
    f16* d = smem + tOff;
    const int ks = (kt + 2 < nk) ? (kt + 2) : nk - 1;
    const f16x8 ic_now = ic0;
    ic0 = ic1;
    ic1 = *(const f16x8*)(gic + ks * 32);   // for kt+2
    f16x8 af[4], bf[4];
#pragma unroll
    for (int mt = 0; mt < 4; ++mt) {
      af[mt] = *(const f16x8*)(sa + (wm + mt * 16) * 32 + fbase);
      af[mt] = af[mt] * ic_now;             // e * cs^-1/4 (normal)
      af[mt] = af[mt] * af[mt];             // P = e^2 / sqrt(cs)
    }
#pragma unroll
    for (int nt = 0; nt < 4; ++nt)
      bf[nt] = *(const f16x8*)(sa + 8192 + (wn + nt * 16) * 32 + fbase);
    glds16(gAs + ks * 32,               d + ldst);
    glds16(gAs + ks * 32 + 128l * NPTS, d + 4096 + ldst);
    glds16(gBs + ks * 32,               d + 8192 + ldst);
#pragma unroll
    for (int mt = 0; mt < 4; ++mt)
#pragma unroll
      for (int nt = 0; nt < 4; ++nt)
        acc[mt][nt] = __builtin_amdgcn_mfma_f32_16x16x32_f16(af[mt], bf[nt], acc[mt][nt], 0, 0, 0);
    asm volatile("s_waitcnt vmcnt(4)" ::: "memory");  // tile kt+1 resident
    __builtin_amdgcn_s_barrier();
    asm volatile("" ::: "memory");
    cOff += BUF3; if (cOff == 3 * BUF3) cOff = 0;
    tOff += BUF3; if (tOff == 3 * BUF3) tOff = 0;
  }

  float* part = split ? part1 : part0;
  const int rbase = (l >> 4) * 4;
#pragma unroll
  for (int mt = 0; mt < 4; ++mt) {
#pragma unroll
    for (int g = 0; g < 4; ++g) {
      const long row = bi + wm + mt * 16 + rbase + g;
      float* Prow = part + row * DIM + bj + wn + lr;
#pragma unroll
      for (int nt = 0; nt < 4; ++nt)
        Prow[nt * 16] = acc[mt][nt][g];
    }
  }
}

extern "C" void kernel_launch(void* const* d_in, const int* in_sizes, int n_in,
                              void* d_out, int out_size, void* d_ws, size_t ws_size,
                              hipStream_t stream) {
  const float* p  = (const float*)d_in[0];
  const float* r  = (const float*)d_in[1];
  const float* Wh = (const float*)d_in[2];
  const float* bh = (const float*)d_in[3];
  const float* Wl = (const float*)d_in[4];
  const float* bl = (const float*)d_in[5];
  const float* Wg = (const float*)d_in[6];
  const float* bg = (const float*)d_in[7];
  float* out = (float*)d_out;

  char* ws = (char*)d_ws;
  f16* q_h  = (f16*)(ws + (0ull  << 20));
  f16* k_h  = (f16*)(ws + (16ull << 20));
  f16* vt_h = (f16*)(ws + (32ull << 20));   // [D,N] v^T, scaled in place
  f16* p_h  = (f16*)(ws + (48ull << 20));
  f16* r_h  = (f16*)(ws + (64ull << 20));
  f16* wh_h = (f16*)(ws + (80ull << 20));
  f16* wl_h = (f16*)(ws + (82ull << 20));
  f16* wg_h = (f16*)(ws + (84ull << 20));
  f16* S    = (f16*)(ws + (96ull << 20));   // 128 MB: exp((s-50)/2) f16
  float* colsum = (float*)(ws + (224ull << 20));
  f16* ics2 = (f16*)(ws + (225ull << 20));
  f16* ics4 = (f16*)(ws + (226ull << 20));
  // PV partials overlay regions dead after QK: q_h/k_h and p_h/r_h (32 MB each)
  float* part0 = (float*)(ws + (0ull  << 20));
  float* part1 = (float*)(ws + (48ull << 20));

  const int nP = NPTS * DIM, nW = DIM * DIM;
  cvt_f32_f16<<<nP / 2048, 256, 0, stream>>>(p,  p_h,  nP);
  cvt_f32_f16<<<nP / 2048, 256, 0, stream>>>(r,  r_h,  nP);
  cvt_f32_f16<<<nW / 2048, 256, 0, stream>>>(Wh, wh_h, nW);
  cvt_f32_f16<<<nW / 2048, 256, 0, stream>>>(Wl, wl_h, nW);
  cvt_f32_f16<<<nW / 2048, 256, 0, stream>>>(Wg, wg_h, nW);
  zero_f32<<<NPTS / 256, 256, 0, stream>>>(colsum, NPTS);

  proj_fused<<<768, dim3(512), 0, stream>>>(p_h, r_h, wh_h, wl_h, wg_h,
                                            bh, bl, bg, q_h, k_h, vt_h);
  gemm_qk<<<2048, dim3(512), 0, stream>>>(q_h, k_h, S, colsum);
  mk_scales<<<NPTS / 256, 256, 0, stream>>>(colsum, ics2, ics4);
  vscale<<<(NPTS / 8) * (DIM / 256), 256, 0, stream>>>(vt_h, ics2);
  gemm_pv<<<512, dim3(512), 0, stream>>>(S, vt_h, ics4, part0, part1);
  reduce_out<<<nP / 1024, 256, 0, stream>>>(p, part0, part1, out);
}

// Round 6
// 523.636 us; speedup vs baseline: 1.0080x; 1.0080x over previous
//
#include <hip/hip_runtime.h>
#include <hip/hip_fp16.h>

typedef _Float16 f16;
typedef __attribute__((ext_vector_type(8))) _Float16 f16x8;
typedef __attribute__((ext_vector_type(4))) float f32x4;

#define NPTS 8192
#define DIM  1024
#define HL2E 0.721347520444482f   // log2(e)/2
#define S2SHIFT 50.0f             // store exp((s-50)/2) in f16
#define TBUF (128 * 32)           // one LDS tile buffer (f16 elems), 128^2 kernels

// async global->LDS, 16B per lane; lds base must be wave-uniform
__device__ __forceinline__ void glds16(const void* g, void* l) {
  __builtin_amdgcn_global_load_lds(
      (const __attribute__((address_space(1))) void*)g,
      (__attribute__((address_space(3))) void*)l, 16, 0, 0);
}

// LDS chunk swizzle (proven: conflicts 1.7e7 -> 0): data chunk kc of row ro
// lives at slot kc ^ ((ro>>1)&3); glds stage lanes fetch global chunk
// (t&3)^((t>>3)&3); frag reads use per-lane base with the same XOR.
//
// R5 lesson (measured): 256x128 tile @2 blocks/CU REGRESSED (159 vs 145 us,
// MfmaUtil 40 vs 45) -- frag-read traffic scales with tile perimeter, so
// halving N raised LDS-pipe work per FLOP 1.33x while doubling LDS-pipe
// sharers. 256x256 @1 block/CU is the balanced-intensity point. This round:
// R4 geometry + T5 setprio around MFMA clusters (waves here are NOT lockstep
// -- one barrier/tile, counted vmcnt -- so the scheduler has read-issuing vs
// MFMA-issuing waves to arbitrate; m218b/m224 regime).

// ---------- small helpers ----------
__global__ void cvt_f32_f16(const float* __restrict__ src, f16* __restrict__ dst, int n) {
  int i = (blockIdx.x * 256 + threadIdx.x) * 8;
  if (i >= n) return;
  const float4* s = (const float4*)(src + i);
  float4 a = s[0], b = s[1];
  f16x8 o;
  o[0] = (f16)a.x; o[1] = (f16)a.y; o[2] = (f16)a.z; o[3] = (f16)a.w;
  o[4] = (f16)b.x; o[5] = (f16)b.y; o[6] = (f16)b.z; o[7] = (f16)b.w;
  *(f16x8*)(dst + i) = o;
}

__global__ void zero_f32(float* __restrict__ p, int n) {
  int i = blockIdx.x * 256 + threadIdx.x;
  if (i < n) p[i] = 0.f;
}

// colsum (= sum of e^2) -> ics2 = cs^-1/2 (for v), ics4 = cs^-1/4 (for P frags)
__global__ void mk_scales(const float* __restrict__ colsum,
                          f16* __restrict__ ics2, f16* __restrict__ ics4) {
  int j = blockIdx.x * 256 + threadIdx.x;
  float r2 = rsqrtf(fmaxf(colsum[j], 1e-20f));
  ics2[j] = (f16)r2;
  ics4[j] = (f16)sqrtf(r2);
}

// vt[n][j] *= ics2[j]  (in place, 8-wide packed)
__global__ void vscale(f16* __restrict__ vt, const f16* __restrict__ ics2) {
  long i = ((long)blockIdx.x * 256 + threadIdx.x) * 8;
  f16x8 v = *(f16x8*)(vt + i);
  f16x8 s = *(const f16x8*)(ics2 + (i & (NPTS - 1)));
  *(f16x8*)(vt + i) = v * s;
}

// out = p + part0 + part1  (PV split-K combine + residual)
__global__ void reduce_out(const float* __restrict__ p,
                           const float* __restrict__ pa,
                           const float* __restrict__ pb,
                           float* __restrict__ out) {
  long i = ((long)blockIdx.x * 256 + threadIdx.x) * 4;
  float4 a = *(const float4*)(p + i);
  float4 b = *(const float4*)(pa + i);
  float4 c = *(const float4*)(pb + i);
  a.x += b.x + c.x; a.y += b.y + c.y; a.z += b.z + c.z; a.w += b.w + c.w;
  *(float4*)(out + i) = a;
}

// ---------- fused projections: q = p@Wh^T+bh, k = r@Wl^T+bl, vt = (p@Wg^T+bg)^T ----------
__global__ __launch_bounds__(256, 2)
void proj_fused(const f16* __restrict__ p_h, const f16* __restrict__ r_h,
                const f16* __restrict__ Wh, const f16* __restrict__ Wl,
                const f16* __restrict__ Wg,
                const float* __restrict__ bh, const float* __restrict__ bl,
                const float* __restrict__ bg,
                f16* __restrict__ q_h, f16* __restrict__ k_h,
                f16* __restrict__ vt_h) {
  __shared__ f16 sA[2 * TBUF];
  __shared__ f16 sB[2 * TBUF];
  const int sub = blockIdx.x >> 9;
  const int bl_ = blockIdx.x & 511;
  const long bi = (long)(bl_ & 63) * 128;
  const long bj = (long)(bl_ >> 6) * 128;
  const f16* A = (sub == 1) ? r_h : p_h;
  const f16* B = (sub == 0) ? Wh : (sub == 1) ? Wl : Wg;
  const float* bias = (sub == 0) ? bh : (sub == 1) ? bl : bg;

  const int t = threadIdx.x;
  const int w = t >> 6, l = t & 63;
  const int wm = (w >> 1) * 64, wn = (w & 1) * 64;
  const int lr = l & 15;
  const int fbase = lr * 32 + (((l >> 4) ^ ((lr >> 1) & 3)) * 8);
  const int grow = w * 16 + (l >> 2);
  const int gcol = ((l & 3) ^ ((l >> 3) & 3)) * 8;
  const f16* gA = A + (bi + grow) * (long)DIM + gcol;
  const f16* gB = B + (bj + grow) * (long)DIM + gcol;
  const int lw0 = (w * 16) * 32, lw1 = (64 + w * 16) * 32;

  glds16(gA, sA + lw0);
  glds16(gA + 64l * DIM, sA + lw1);
  glds16(gB, sB + lw0);
  glds16(gB + 64l * DIM, sB + lw1);
  gA += 32; gB += 32;

  f32x4 acc[4][4] = {};
  const int nk = DIM / 32;
  for (int k = 0; k < nk; k++) {
    const int cur = (k & 1) * TBUF, nxt = TBUF - cur;
    __syncthreads();
    if (k + 1 < nk) {
      glds16(gA, sA + nxt + lw0);
      glds16(gA + 64l * DIM, sA + nxt + lw1);
      glds16(gB, sB + nxt + lw0);
      glds16(gB + 64l * DIM, sB + nxt + lw1);
      gA += 32; gB += 32;
    }
    f16x8 af[4], bf[4];
#pragma unroll
    for (int mt = 0; mt < 4; mt++)
      af[mt] = *(const f16x8*)(sA + cur + (wm + mt * 16) * 32 + fbase);
#pragma unroll
    for (int nt = 0; nt < 4; nt++)
      bf[nt] = *(const f16x8*)(sB + cur + (wn + nt * 16) * 32 + fbase);
#pragma unroll
    for (int mt = 0; mt < 4; mt++)
#pragma unroll
      for (int nt = 0; nt < 4; nt++)
        acc[mt][nt] = __builtin_amdgcn_mfma_f32_16x16x32_f16(af[mt], bf[nt], acc[mt][nt], 0, 0, 0);
  }

  const int rbase = (l >> 4) * 4;
  f16* C = (sub == 0) ? q_h : (sub == 1) ? k_h : vt_h;
#pragma unroll
  for (int nt = 0; nt < 4; nt++) {
    const long col = bj + wn + nt * 16 + lr;
    const float bb = bias[col];
#pragma unroll
    for (int mt = 0; mt < 4; mt++) {
      const long row0 = bi + wm + mt * 16 + rbase;
      if (sub < 2) {
#pragma unroll
        for (int g = 0; g < 4; g++)
          C[(row0 + g) * DIM + col] = (f16)(acc[mt][nt][g] + bb);
      } else {
        union { unsigned long long u; f16 h[4]; } pk;
#pragma unroll
        for (int g = 0; g < 4; g++) pk.h[g] = (f16)(acc[mt][nt][g] + bb);
        *(unsigned long long*)(C + col * (long)NPTS + row0) = pk.u;
      }
    }
  }
}

// ---------- QK^T: S = exp((s-50)/2) f16, fused column sum of squares ----------
// 256x256 tile, BK=32, 512 thr (8 waves 2Mx4N), 4 LDS tile-buffers (128 KB),
// staging 3 K-tiles ahead. ONE raw s_barrier + ONE counted s_waitcnt vmcnt(8)
// per K-tile (never vmcnt(0) in the loop). Race safety: slot (kt+3)&3 ==
// (kt-1)&3; reads of buf kt-1 finished before barrier(kt-1) which precedes the
// stage issue in tile kt; per-wave vmcnt(8) before barrier(kt) => tile kt+1
// fully resident for ALL waves after barrier(kt). Tail re-stages tile 31.
// T5: setprio(1) around each 16-MFMA cluster -- waves desync in the
// inter-barrier window, so the CU scheduler can prefer MFMA-issuing waves
// while others burst ds_reads/glds.
// XCD swizzle: sx=b&7 pins 4 k-panels (2 MB) per XCD L2.
__global__ __launch_bounds__(512, 2)
void gemm_qk(const f16* __restrict__ A, const f16* __restrict__ B,
             f16* __restrict__ S, float* __restrict__ colsum) {
  __shared__ f16 smem[4 * 16384];   // 4 bufs x (A 8192 f16 | B 8192 f16) = 128 KB
  const int b = blockIdx.x;
  const int sx = b & 7;             // XCD id
  const int j = b >> 3;             // 0..127
  const long bi = (long)(j >> 2) * 256;
  const long bj = (long)(sx * 4 + (j & 3)) * 256;

  const int t = threadIdx.x;
  const int w = t >> 6, l = t & 63;
  const int wm = (w >> 2) * 128, wn = (w & 3) * 64;   // per-wave C: 128x64
  const int lr = l & 15;
  const int fbase = lr * 32 + (((l >> 4) ^ ((lr >> 1) & 3)) * 8);
  const int sro = t >> 2;
  const int scol = ((t & 3) ^ ((t >> 3) & 3)) * 8;
  const f16* gAs = A + (bi + sro) * (long)DIM + scol;
  const f16* gBs = B + (bj + sro) * (long)DIM + scol;
  const int ldst = w * 512;         // wave-uniform lane-base within a half (f16)

#pragma unroll
  for (int tl = 0; tl < 3; ++tl) {
    f16* d = smem + tl * 16384;
    glds16(gAs + tl * 32,              d + ldst);
    glds16(gAs + tl * 32 + 128l * DIM, d + 4096 + ldst);
    glds16(gBs + tl * 32,              d + 8192 + ldst);
    glds16(gBs + tl * 32 + 128l * DIM, d + 12288 + ldst);
  }
  asm volatile("s_waitcnt vmcnt(8)" ::: "memory");
  __builtin_amdgcn_s_barrier();
  asm volatile("" ::: "memory");

  f32x4 acc[8][4] = {};
#pragma unroll 4
  for (int kt = 0; kt < 32; ++kt) {
    const f16* sa = smem + (kt & 3) * 16384;
    f16* d = smem + ((kt + 3) & 3) * 16384;
    const int ks = (kt + 3 < 32) ? (kt + 3) : 31;    // clamped tail re-stage
    const f16* as_ = gAs + ks * 32;
    const f16* bs_ = gBs + ks * 32;
    f16x8 af[4], bf[4];

    // phase 1: rows wm..wm+63 ; stage A halves of tile kt+3
#pragma unroll
    for (int mt = 0; mt < 4; ++mt)
      af[mt] = *(const f16x8*)(sa + (wm + mt * 16) * 32 + fbase);
#pragma unroll
    for (int nt = 0; nt < 4; ++nt)
      bf[nt] = *(const f16x8*)(sa + 8192 + (wn + nt * 16) * 32 + fbase);
    glds16(as_,              d + ldst);
    glds16(as_ + 128l * DIM, d + 4096 + ldst);
    __builtin_amdgcn_s_setprio(1);
#pragma unroll
    for (int mt = 0; mt < 4; ++mt)
#pragma unroll
      for (int nt = 0; nt < 4; ++nt)
        acc[mt][nt] = __builtin_amdgcn_mfma_f32_16x16x32_f16(af[mt], bf[nt], acc[mt][nt], 0, 0, 0);
    __builtin_amdgcn_s_setprio(0);

    // phase 2: rows wm+64..wm+127 (bf reused); stage B halves of tile kt+3
#pragma unroll
    for (int mt = 0; mt < 4; ++mt)
      af[mt] = *(const f16x8*)(sa + (wm + 64 + mt * 16) * 32 + fbase);
    glds16(bs_,              d + 8192 + ldst);
    glds16(bs_ + 128l * DIM, d + 12288 + ldst);
    __builtin_amdgcn_s_setprio(1);
#pragma unroll
    for (int mt = 0; mt < 4; ++mt)
#pragma unroll
      for (int nt = 0; nt < 4; ++nt)
        acc[4 + mt][nt] = __builtin_amdgcn_mfma_f32_16x16x32_f16(af[mt], bf[nt], acc[4 + mt][nt], 0, 0, 0);
    __builtin_amdgcn_s_setprio(0);

    asm volatile("s_waitcnt vmcnt(8)" ::: "memory"); // tile kt+1 resident; never 0
    __builtin_amdgcn_s_barrier();
    asm volatile("" ::: "memory");
  }

  // epilogue: e = exp((s-50)/2) clamped to 240 (f16-normal; sqrt-split keeps
  // all stored factors away from subnormals — R3 lesson). colsum sums ef^2 of
  // the SAME f16 values PV reads. nt innermost: 64B-line-grouped stores.
  const int rbase = (l >> 4) * 4;
  float csum[4] = {0.f, 0.f, 0.f, 0.f};
#pragma unroll
  for (int mt = 0; mt < 8; ++mt) {
#pragma unroll
    for (int g = 0; g < 4; ++g) {
      const long row = bi + wm + mt * 16 + rbase + g;
      f16* Srow = S + row * NPTS + bj + wn + lr;
#pragma unroll
      for (int nt = 0; nt < 4; ++nt) {
        float e = exp2f((acc[mt][nt][g] - S2SHIFT) * HL2E);
        e = fminf(e, 240.f);              // e^2 <= 57600 < f16 max
        f16 eh = (f16)e;
        Srow[nt * 16] = eh;
        float ef = (float)eh;
        csum[nt] += ef * ef;
      }
    }
  }
#pragma unroll
  for (int nt = 0; nt < 4; ++nt) {
    float cs = csum[nt];
    cs += __shfl_xor(cs, 16);
    cs += __shfl_xor(cs, 32);
    if (l < 16) atomicAdd(colsum + (bj + wn + nt * 16 + lr), cs);
  }
}

// ---------- PV split-K x2: part[s] = ((S.ics4)^2) @ v~ ----------
// Same schedule as gemm_qk (4 bufs, 3-ahead glds, 1 barrier + counted vmcnt
// per K-tile) + T5 setprio around MFMA clusters. A-side is RAW e staged via
// glds16; the P transform happens at frag-read time in registers:
// P = (e * cs^-1/4)^2 -- multiply FIRST then square, so every intermediate
// stays f16-normal (R3 lesson). All 8 M-frags of a thread share K-chunk l>>4,
// so ONE f16x8 of ics4 per thread per K-tile (icf, double-buffered 2 tiles
// ahead; static &1 index under unroll 4). 5 vmem issues per tile (1 icf +
// 4 glds) -> counted wait vmcnt(10) (= 2 tiles' issues) guarantees buffer
// kt+1 resident. Grid 256 = 32 bi x 4 bj x 2 splits, 1 block/CU, single
// round; the 4 bj-blocks sharing an A-panel (2 MB of S) land on one XCD.
__global__ __launch_bounds__(512, 2)
void gemm_pv(const f16* __restrict__ Sm, const f16* __restrict__ vt,
             const f16* __restrict__ ics4,
             float* __restrict__ part0, float* __restrict__ part1) {
  __shared__ f16 smem[4 * 16384];
  const int b = blockIdx.x;         // 0..255
  const int sx = b & 7;             // XCD id
  const int q = b >> 3;             // 0..31
  const int bjidx = q & 3;
  const int pr = (q >> 2) * 8 + sx; // pair (split,bi) 0..63; pr&7 == sx
  const int split = pr >> 5;
  const long bi = (long)(pr & 31) * 256;
  const long bj = (long)bjidx * 256;
  const long koff = (long)split * (NPTS / 2);

  const int t = threadIdx.x;
  const int w = t >> 6, l = t & 63;
  const int wm = (w >> 2) * 128, wn = (w & 3) * 64;
  const int lr = l & 15;
  const int fbase = lr * 32 + (((l >> 4) ^ ((lr >> 1) & 3)) * 8);
  const int sro = t >> 2;
  const int scol = ((t & 3) ^ ((t >> 3) & 3)) * 8;
  const f16* gAs = Sm + (bi + sro) * (long)NPTS + koff + scol;
  const f16* gBs = vt + (bj + sro) * (long)NPTS + koff + scol;
  const f16* gic = ics4 + koff + (l >> 4) * 8;   // frag K-chunk for this lane
  const int ldst = w * 512;

  const int nk = (NPTS / 2) / 32;   // 128 K-tiles per split

  f16x8 icf[2];
  icf[0] = *(const f16x8*)(gic);
  icf[1] = *(const f16x8*)(gic + 32);
#pragma unroll
  for (int tl = 0; tl < 3; ++tl) {
    f16* d = smem + tl * 16384;
    glds16(gAs + tl * 32,               d + ldst);
    glds16(gAs + tl * 32 + 128l * NPTS, d + 4096 + ldst);
    glds16(gBs + tl * 32,               d + 8192 + ldst);
    glds16(gBs + tl * 32 + 128l * NPTS, d + 12288 + ldst);
  }
  asm volatile("s_waitcnt vmcnt(8)" ::: "memory");  // icf0/1 + tile 0 landed
  __builtin_amdgcn_s_barrier();
  asm volatile("" ::: "memory");

  f32x4 acc[8][4] = {};
#pragma unroll 4
  for (int kt = 0; kt < nk; ++kt) {
    const f16* sa = smem + (kt & 3) * 16384;
    f16* d = smem + ((kt + 3) & 3) * 16384;
    const int ks = (kt + 3 < nk) ? (kt + 3) : nk - 1;  // clamped tail re-stage
    const int ki = (kt + 2 < nk) ? (kt + 2) : nk - 1;
    const f16* as_ = gAs + ks * 32;
    const f16* bs_ = gBs + ks * 32;
    f16x8 af[4], bf[4];

    const f16x8 ic_now = icf[kt & 1];                 // consume (loaded at kt-2)
    icf[kt & 1] = *(const f16x8*)(gic + ki * 32);     // reload slot for kt+2

    // phase 1: rows wm..wm+63 ; stage A halves of tile kt+3
#pragma unroll
    for (int mt = 0; mt < 4; ++mt) {
      af[mt] = *(const f16x8*)(sa + (wm + mt * 16) * 32 + fbase);
      af[mt] = af[mt] * ic_now;                       // e * cs^-1/4 (normal)
      af[mt] = af[mt] * af[mt];                       // P = e^2 / sqrt(cs)
    }
#pragma unroll
    for (int nt = 0; nt < 4; ++nt)
      bf[nt] = *(const f16x8*)(sa + 8192 + (wn + nt * 16) * 32 + fbase);
    glds16(as_,               d + ldst);
    glds16(as_ + 128l * NPTS, d + 4096 + ldst);
    __builtin_amdgcn_s_setprio(1);
#pragma unroll
    for (int mt = 0; mt < 4; ++mt)
#pragma unroll
      for (int nt = 0; nt < 4; ++nt)
        acc[mt][nt] = __builtin_amdgcn_mfma_f32_16x16x32_f16(af[mt], bf[nt], acc[mt][nt], 0, 0, 0);
    __builtin_amdgcn_s_setprio(0);

    // phase 2: rows wm+64..wm+127 (bf reused); stage B halves of tile kt+3
#pragma unroll
    for (int mt = 0; mt < 4; ++mt) {
      af[mt] = *(const f16x8*)(sa + (wm + 64 + mt * 16) * 32 + fbase);
      af[mt] = af[mt] * ic_now;
      af[mt] = af[mt] * af[mt];
    }
    glds16(bs_,               d + 8192 + ldst);
    glds16(bs_ + 128l * NPTS, d + 12288 + ldst);
    __builtin_amdgcn_s_setprio(1);
#pragma unroll
    for (int mt = 0; mt < 4; ++mt)
#pragma unroll
      for (int nt = 0; nt < 4; ++nt)
        acc[4 + mt][nt] = __builtin_amdgcn_mfma_f32_16x16x32_f16(af[mt], bf[nt], acc[4 + mt][nt], 0, 0, 0);
    __builtin_amdgcn_s_setprio(0);

    asm volatile("s_waitcnt vmcnt(10)" ::: "memory"); // tile kt+1 resident
    __builtin_amdgcn_s_barrier();
    asm volatile("" ::: "memory");
  }

  float* part = split ? part1 : part0;
  const int rbase = (l >> 4) * 4;
#pragma unroll
  for (int mt = 0; mt < 8; ++mt) {
#pragma unroll
    for (int g = 0; g < 4; ++g) {
      const long row = bi + wm + mt * 16 + rbase + g;
      float* Prow = part + row * DIM + bj + wn + lr;
#pragma unroll
      for (int nt = 0; nt < 4; ++nt)
        Prow[nt * 16] = acc[mt][nt][g];
    }
  }
}

extern "C" void kernel_launch(void* const* d_in, const int* in_sizes, int n_in,
                              void* d_out, int out_size, void* d_ws, size_t ws_size,
                              hipStream_t stream) {
  const float* p  = (const float*)d_in[0];
  const float* r  = (const float*)d_in[1];
  const float* Wh = (const float*)d_in[2];
  const float* bh = (const float*)d_in[3];
  const float* Wl = (const float*)d_in[4];
  const float* bl = (const float*)d_in[5];
  const float* Wg = (const float*)d_in[6];
  const float* bg = (const float*)d_in[7];
  float* out = (float*)d_out;

  char* ws = (char*)d_ws;
  f16* q_h  = (f16*)(ws + (0ull  << 20));
  f16* k_h  = (f16*)(ws + (16ull << 20));
  f16* vt_h = (f16*)(ws + (32ull << 20));   // [D,N] v^T, scaled in place
  f16* p_h  = (f16*)(ws + (48ull << 20));
  f16* r_h  = (f16*)(ws + (64ull << 20));
  f16* wh_h = (f16*)(ws + (80ull << 20));
  f16* wl_h = (f16*)(ws + (82ull << 20));
  f16* wg_h = (f16*)(ws + (84ull << 20));
  f16* S    = (f16*)(ws + (96ull << 20));   // 128 MB: exp((s-50)/2) f16
  float* colsum = (float*)(ws + (224ull << 20));
  f16* ics2 = (f16*)(ws + (225ull << 20));
  f16* ics4 = (f16*)(ws + (226ull << 20));
  // PV partials overlay regions dead after QK: q_h/k_h and p_h/r_h (32 MB each)
  float* part0 = (float*)(ws + (0ull  << 20));
  float* part1 = (float*)(ws + (48ull << 20));

  const int nP = NPTS * DIM, nW = DIM * DIM;
  cvt_f32_f16<<<nP / 2048, 256, 0, stream>>>(p,  p_h,  nP);
  cvt_f32_f16<<<nP / 2048, 256, 0, stream>>>(r,  r_h,  nP);
  cvt_f32_f16<<<nW / 2048, 256, 0, stream>>>(Wh, wh_h, nW);
  cvt_f32_f16<<<nW / 2048, 256, 0, stream>>>(Wl, wl_h, nW);
  cvt_f32_f16<<<nW / 2048, 256, 0, stream>>>(Wg, wg_h, nW);
  zero_f32<<<NPTS / 256, 256, 0, stream>>>(colsum, NPTS);

  dim3 blk(256);
  proj_fused<<<1536, blk, 0, stream>>>(p_h, r_h, wh_h, wl_h, wg_h,
                                       bh, bl, bg, q_h, k_h, vt_h);
  gemm_qk<<<1024, dim3(512), 0, stream>>>(q_h, k_h, S, colsum);
  mk_scales<<<NPTS / 256, 256, 0, stream>>>(colsum, ics2, ics4);
  vscale<<<(NPTS / 8) * (DIM / 256), 256, 0, stream>>>(vt_h, ics2);
  gemm_pv<<<256, dim3(512), 0, stream>>>(S, vt_h, ics4, part0, part1);
  reduce_out<<<nP / 1024, 256, 0, stream>>>(p, part0, part1, out);
}

// Round 8
// 492.823 us; speedup vs baseline: 1.0710x; 1.0625x over previous
//
#include <hip/hip_runtime.h>
#include <hip/hip_fp16.h>

typedef _Float16 f16;
typedef __attribute__((ext_vector_type(8))) _Float16 f16x8;
typedef __attribute__((ext_vector_type(4))) float f32x4;

#define NPTS 8192
#define DIM  1024
#define HL2E 0.721347520444482f   // log2(e)/2
#define S2SHIFT 50.0f             // store exp((s-50)/2) in f16
#define TBUF (128 * 32)           // one LDS tile buffer (f16 elems), 128^2 kernels

// async global->LDS, 16B per lane; lds base must be wave-uniform
__device__ __forceinline__ void glds16(const void* g, void* l) {
  __builtin_amdgcn_global_load_lds(
      (const __attribute__((address_space(1))) void*)g,
      (__attribute__((address_space(3))) void*)l, 16, 0, 0);
}

// LDS chunk swizzle (proven: conflicts 1.7e7 -> 0): data chunk kc of row ro
// lives at slot kc ^ ((ro>>1)&3); glds stage lanes fetch global chunk
// (t&3)^((t>>3)&3); frag reads use per-lane base with the same XOR.
//
// R5: 256x128 @2 blocks/CU regressed (perimeter-scaled LDS traffic).
// R6: setprio null-to-negative (waves re-converge at tile barriers).
// R7: crashed on a macro self-init bug (const int kt = (kt);) -- NOT a
//     schedule fault. Fixed here (kq/kp inner names) + ic clobber fix
//     (copy icn BEFORE reloading the ring slot).
// Schedule: cross-tile frag pipeline. Staging runs 3 tiles ahead; counted
// wait vmcnt(4) at end of body kt retires all loads through tile kt+2, so
// buffer kt+1 is stable at the START of body kt. Each body pre-reads tile
// kt+1's phase-1 frags into the alternate named register set during tile
// kt's MFMAs -> tile-start MFMA has no ds_read dependency.

// ---------- small helpers ----------
__global__ void cvt_f32_f16(const float* __restrict__ src, f16* __restrict__ dst, int n) {
  int i = (blockIdx.x * 256 + threadIdx.x) * 8;
  if (i >= n) return;
  const float4* s = (const float4*)(src + i);
  float4 a = s[0], b = s[1];
  f16x8 o;
  o[0] = (f16)a.x; o[1] = (f16)a.y; o[2] = (f16)a.z; o[3] = (f16)a.w;
  o[4] = (f16)b.x; o[5] = (f16)b.y; o[6] = (f16)b.z; o[7] = (f16)b.w;
  *(f16x8*)(dst + i) = o;
}

__global__ void zero_f32(float* __restrict__ p, int n) {
  int i = blockIdx.x * 256 + threadIdx.x;
  if (i < n) p[i] = 0.f;
}

// colsum (= sum of e^2) -> ics2 = cs^-1/2 (for v), ics4 = cs^-1/4 (for P frags)
__global__ void mk_scales(const float* __restrict__ colsum,
                          f16* __restrict__ ics2, f16* __restrict__ ics4) {
  int j = blockIdx.x * 256 + threadIdx.x;
  float r2 = rsqrtf(fmaxf(colsum[j], 1e-20f));
  ics2[j] = (f16)r2;
  ics4[j] = (f16)sqrtf(r2);
}

// vt[n][j] *= ics2[j]  (in place, 8-wide packed)
__global__ void vscale(f16* __restrict__ vt, const f16* __restrict__ ics2) {
  long i = ((long)blockIdx.x * 256 + threadIdx.x) * 8;
  f16x8 v = *(f16x8*)(vt + i);
  f16x8 s = *(const f16x8*)(ics2 + (i & (NPTS - 1)));
  *(f16x8*)(vt + i) = v * s;
}

// out = p + part0 + part1  (PV split-K combine + residual)
__global__ void reduce_out(const float* __restrict__ p,
                           const float* __restrict__ pa,
                           const float* __restrict__ pb,
                           float* __restrict__ out) {
  long i = ((long)blockIdx.x * 256 + threadIdx.x) * 4;
  float4 a = *(const float4*)(p + i);
  float4 b = *(const float4*)(pa + i);
  float4 c = *(const float4*)(pb + i);
  a.x += b.x + c.x; a.y += b.y + c.y; a.z += b.z + c.z; a.w += b.w + c.w;
  *(float4*)(out + i) = a;
}

// ---------- fused projections: q = p@Wh^T+bh, k = r@Wl^T+bl, vt = (p@Wg^T+bg)^T ----------
__global__ __launch_bounds__(256, 2)
void proj_fused(const f16* __restrict__ p_h, const f16* __restrict__ r_h,
                const f16* __restrict__ Wh, const f16* __restrict__ Wl,
                const f16* __restrict__ Wg,
                const float* __restrict__ bh, const float* __restrict__ bl,
                const float* __restrict__ bg,
                f16* __restrict__ q_h, f16* __restrict__ k_h,
                f16* __restrict__ vt_h) {
  __shared__ f16 sA[2 * TBUF];
  __shared__ f16 sB[2 * TBUF];
  const int sub = blockIdx.x >> 9;
  const int bl_ = blockIdx.x & 511;
  const long bi = (long)(bl_ & 63) * 128;
  const long bj = (long)(bl_ >> 6) * 128;
  const f16* A = (sub == 1) ? r_h : p_h;
  const f16* B = (sub == 0) ? Wh : (sub == 1) ? Wl : Wg;
  const float* bias = (sub == 0) ? bh : (sub == 1) ? bl : bg;

  const int t = threadIdx.x;
  const int w = t >> 6, l = t & 63;
  const int wm = (w >> 1) * 64, wn = (w & 1) * 64;
  const int lr = l & 15;
  const int fbase = lr * 32 + (((l >> 4) ^ ((lr >> 1) & 3)) * 8);
  const int grow = w * 16 + (l >> 2);
  const int gcol = ((l & 3) ^ ((l >> 3) & 3)) * 8;
  const f16* gA = A + (bi + grow) * (long)DIM + gcol;
  const f16* gB = B + (bj + grow) * (long)DIM + gcol;
  const int lw0 = (w * 16) * 32, lw1 = (64 + w * 16) * 32;

  glds16(gA, sA + lw0);
  glds16(gA + 64l * DIM, sA + lw1);
  glds16(gB, sB + lw0);
  glds16(gB + 64l * DIM, sB + lw1);
  gA += 32; gB += 32;

  f32x4 acc[4][4] = {};
  const int nk = DIM / 32;
  for (int k = 0; k < nk; k++) {
    const int cur = (k & 1) * TBUF, nxt = TBUF - cur;
    __syncthreads();
    if (k + 1 < nk) {
      glds16(gA, sA + nxt + lw0);
      glds16(gA + 64l * DIM, sA + nxt + lw1);
      glds16(gB, sB + nxt + lw0);
      glds16(gB + 64l * DIM, sB + nxt + lw1);
      gA += 32; gB += 32;
    }
    f16x8 af[4], bf[4];
#pragma unroll
    for (int mt = 0; mt < 4; mt++)
      af[mt] = *(const f16x8*)(sA + cur + (wm + mt * 16) * 32 + fbase);
#pragma unroll
    for (int nt = 0; nt < 4; nt++)
      bf[nt] = *(const f16x8*)(sB + cur + (wn + nt * 16) * 32 + fbase);
#pragma unroll
    for (int mt = 0; mt < 4; mt++)
#pragma unroll
      for (int nt = 0; nt < 4; nt++)
        acc[mt][nt] = __builtin_amdgcn_mfma_f32_16x16x32_f16(af[mt], bf[nt], acc[mt][nt], 0, 0, 0);
  }

  const int rbase = (l >> 4) * 4;
  f16* C = (sub == 0) ? q_h : (sub == 1) ? k_h : vt_h;
#pragma unroll
  for (int nt = 0; nt < 4; nt++) {
    const long col = bj + wn + nt * 16 + lr;
    const float bb = bias[col];
#pragma unroll
    for (int mt = 0; mt < 4; mt++) {
      const long row0 = bi + wm + mt * 16 + rbase;
      if (sub < 2) {
#pragma unroll
        for (int g = 0; g < 4; g++)
          C[(row0 + g) * DIM + col] = (f16)(acc[mt][nt][g] + bb);
      } else {
        union { unsigned long long u; f16 h[4]; } pk;
#pragma unroll
        for (int g = 0; g < 4; g++) pk.h[g] = (f16)(acc[mt][nt][g] + bb);
        *(unsigned long long*)(C + col * (long)NPTS + row0) = pk.u;
      }
    }
  }
}

// ---------- QK^T: S = exp((s-50)/2) f16, fused column sum of squares ----------
// 256x256, BK=32, 512 thr (8 waves 2Mx4N), 4 LDS bufs, 3-ahead staging.
// Cross-tile frag pipeline (see header). Race: stage target slot (kq+3)&3 ==
// (kq-1)&3, whose reads completed before barrier(kq-1); vmcnt(4) at end of
// body kq retires all loads through tile kq+2 (issued >=1 body earlier,
// ~2700cyc >> 900cyc HBM latency) -> pre-read of tile kq+1 in body kq safe.
// XCD swizzle: sx=b&7 pins 4 k-panels (2 MB) per XCD L2.
#define QK_BODY(KT, PA, PB, NA, NB)                                          \
  {                                                                          \
    const int kq = (KT);                                                     \
    const f16* sa = smem + (kq & 3) * 16384;                                 \
    const int ksn = (kq + 1 < 32) ? (kq + 1) : 31;                           \
    const f16* sn = smem + (ksn & 3) * 16384;                                \
    f16* d = smem + ((kq + 3) & 3) * 16384;                                  \
    const int ks = (kq + 3 < 32) ? (kq + 3) : 31;                            \
    const f16* as_ = gAs + ks * 32;                                          \
    const f16* bs_ = gBs + ks * 32;                                          \
    f16x8 af2[4];                                                            \
    _Pragma("unroll") for (int mt = 0; mt < 4; ++mt)                         \
      af2[mt] = *(const f16x8*)(sa + (wm + 64 + mt * 16) * 32 + fbase);      \
    glds16(as_,              d + ldst);                                      \
    glds16(as_ + 128l * DIM, d + 4096 + ldst);                               \
    _Pragma("unroll") for (int mt = 0; mt < 4; ++mt)                         \
      _Pragma("unroll") for (int nt = 0; nt < 4; ++nt)                       \
        acc[mt][nt] = __builtin_amdgcn_mfma_f32_16x16x32_f16(                \
            PA[mt], PB[nt], acc[mt][nt], 0, 0, 0);                           \
    glds16(bs_,              d + 8192 + ldst);                               \
    glds16(bs_ + 128l * DIM, d + 12288 + ldst);                              \
    _Pragma("unroll") for (int mt = 0; mt < 4; ++mt)                         \
      _Pragma("unroll") for (int nt = 0; nt < 4; ++nt)                       \
        acc[4 + mt][nt] = __builtin_amdgcn_mfma_f32_16x16x32_f16(            \
            af2[mt], PB[nt], acc[4 + mt][nt], 0, 0, 0);                      \
    _Pragma("unroll") for (int mt = 0; mt < 4; ++mt)                         \
      NA[mt] = *(const f16x8*)(sn + (wm + mt * 16) * 32 + fbase);            \
    _Pragma("unroll") for (int nt = 0; nt < 4; ++nt)                         \
      NB[nt] = *(const f16x8*)(sn + 8192 + (wn + nt * 16) * 32 + fbase);     \
    asm volatile("s_waitcnt vmcnt(4)" ::: "memory");                         \
    __builtin_amdgcn_s_barrier();                                            \
    asm volatile("" ::: "memory");                                           \
  }

__global__ __launch_bounds__(512, 2)
void gemm_qk(const f16* __restrict__ A, const f16* __restrict__ B,
             f16* __restrict__ S, float* __restrict__ colsum) {
  __shared__ f16 smem[4 * 16384];   // 4 bufs x (A 8192 f16 | B 8192 f16) = 128 KB
  const int b = blockIdx.x;
  const int sx = b & 7;             // XCD id
  const int j = b >> 3;             // 0..127
  const long bi = (long)(j >> 2) * 256;
  const long bj = (long)(sx * 4 + (j & 3)) * 256;

  const int t = threadIdx.x;
  const int w = t >> 6, l = t & 63;
  const int wm = (w >> 2) * 128, wn = (w & 3) * 64;   // per-wave C: 128x64
  const int lr = l & 15;
  const int fbase = lr * 32 + (((l >> 4) ^ ((lr >> 1) & 3)) * 8);
  const int sro = t >> 2;
  const int scol = ((t & 3) ^ ((t >> 3) & 3)) * 8;
  const f16* gAs = A + (bi + sro) * (long)DIM + scol;
  const f16* gBs = B + (bj + sro) * (long)DIM + scol;
  const int ldst = w * 512;         // wave-uniform lane-base within a half (f16)

#pragma unroll
  for (int tl = 0; tl < 3; ++tl) {
    f16* d = smem + tl * 16384;
    glds16(gAs + tl * 32,              d + ldst);
    glds16(gAs + tl * 32 + 128l * DIM, d + 4096 + ldst);
    glds16(gBs + tl * 32,              d + 8192 + ldst);
    glds16(gBs + tl * 32 + 128l * DIM, d + 12288 + ldst);
  }
  asm volatile("s_waitcnt vmcnt(4)" ::: "memory");   // tiles 0,1 landed
  __builtin_amdgcn_s_barrier();
  asm volatile("" ::: "memory");

  f32x4 acc[8][4] = {};
  f16x8 a0[4], b0[4], a1[4], b1[4];
#pragma unroll
  for (int mt = 0; mt < 4; ++mt)
    a0[mt] = *(const f16x8*)(smem + (wm + mt * 16) * 32 + fbase);
#pragma unroll
  for (int nt = 0; nt < 4; ++nt)
    b0[nt] = *(const f16x8*)(smem + 8192 + (wn + nt * 16) * 32 + fbase);

  for (int kt = 0; kt < 32; kt += 2) {
    QK_BODY(kt,     a0, b0, a1, b1)
    QK_BODY(kt + 1, a1, b1, a0, b0)
  }

  // epilogue: e = exp((s-50)/2) clamped to 240 (f16-normal; sqrt-split keeps
  // all stored factors away from subnormals -- R3 lesson). colsum sums ef^2 of
  // the SAME f16 values PV reads. nt innermost: 64B-line-grouped stores.
  const int rbase = (l >> 4) * 4;
  float csum[4] = {0.f, 0.f, 0.f, 0.f};
#pragma unroll
  for (int mt = 0; mt < 8; ++mt) {
#pragma unroll
    for (int g = 0; g < 4; ++g) {
      const long row = bi + wm + mt * 16 + rbase + g;
      f16* Srow = S + row * NPTS + bj + wn + lr;
#pragma unroll
      for (int nt = 0; nt < 4; ++nt) {
        float e = exp2f((acc[mt][nt][g] - S2SHIFT) * HL2E);
        e = fminf(e, 240.f);              // e^2 <= 57600 < f16 max
        f16 eh = (f16)e;
        Srow[nt * 16] = eh;
        float ef = (float)eh;
        csum[nt] += ef * ef;
      }
    }
  }
#pragma unroll
  for (int nt = 0; nt < 4; ++nt) {
    float cs = csum[nt];
    cs += __shfl_xor(cs, 16);
    cs += __shfl_xor(cs, 32);
    if (l < 16) atomicAdd(colsum + (bj + wn + nt * 16 + lr), cs);
  }
}

// ---------- PV split-K x2: part[s] = ((S.ics4)^2) @ v~ ----------
// Same cross-tile frag pipeline. icn is COPIED from the ring slot BEFORE the
// slot is reloaded (R7 clobber fix). Transform P = (e*icn)^2 squares in place
// on the dead frag registers (multiply FIRST then square -- R3 lesson).
// 5 vmem issues/body (ic reload + 4 glds) -> vmcnt(5) retires all loads
// through tile kp+2 and the ic for body kp+2. Grid 256 = 32 bi x 4 bj x
// 2 splits; the 4 bj-blocks sharing an A-panel land on one XCD.
#define PV_BODY(KT, PA, PB, NA, NB, ICREG)                                   \
  {                                                                          \
    const int kp = (KT);                                                     \
    const f16* sa = smem + (kp & 3) * 16384;                                 \
    const int ksn = (kp + 1 < nk) ? (kp + 1) : nk - 1;                       \
    const f16* sn = smem + (ksn & 3) * 16384;                                \
    f16* d = smem + ((kp + 3) & 3) * 16384;                                  \
    const int ks = (kp + 3 < nk) ? (kp + 3) : nk - 1;                        \
    const int ki = (kp + 2 < nk) ? (kp + 2) : nk - 1;                        \
    const f16* as_ = gAs + ks * 32;                                          \
    const f16* bs_ = gBs + ks * 32;                                          \
    const f16x8 icn = ICREG;                   /* copy BEFORE reload */      \
    ICREG = *(const f16x8*)(gic + ki * 32);    /* ring slot <- ic(kp+2) */   \
    f16x8 af2[4];                                                            \
    _Pragma("unroll") for (int mt = 0; mt < 4; ++mt)                         \
      af2[mt] = *(const f16x8*)(sa + (wm + 64 + mt * 16) * 32 + fbase);      \
    glds16(as_,               d + ldst);                                     \
    glds16(as_ + 128l * NPTS, d + 4096 + ldst);                              \
    _Pragma("unroll") for (int mt = 0; mt < 4; ++mt) {                       \
      PA[mt] = PA[mt] * icn; PA[mt] = PA[mt] * PA[mt];                       \
    }                                                                        \
    _Pragma("unroll") for (int mt = 0; mt < 4; ++mt)                         \
      _Pragma("unroll") for (int nt = 0; nt < 4; ++nt)                       \
        acc[mt][nt] = __builtin_amdgcn_mfma_f32_16x16x32_f16(                \
            PA[mt], PB[nt], acc[mt][nt], 0, 0, 0);                           \
    glds16(bs_,               d + 8192 + ldst);                              \
    glds16(bs_ + 128l * NPTS, d + 12288 + ldst);                             \
    _Pragma("unroll") for (int mt = 0; mt < 4; ++mt) {                       \
      af2[mt] = af2[mt] * icn; af2[mt] = af2[mt] * af2[mt];                  \
    }                                                                        \
    _Pragma("unroll") for (int mt = 0; mt < 4; ++mt)                         \
      _Pragma("unroll") for (int nt = 0; nt < 4; ++nt)                       \
        acc[4 + mt][nt] = __builtin_amdgcn_mfma_f32_16x16x32_f16(            \
            af2[mt], PB[nt], acc[4 + mt][nt], 0, 0, 0);                      \
    _Pragma("unroll") for (int mt = 0; mt < 4; ++mt)                         \
      NA[mt] = *(const f16x8*)(sn + (wm + mt * 16) * 32 + fbase);            \
    _Pragma("unroll") for (int nt = 0; nt < 4; ++nt)                         \
      NB[nt] = *(const f16x8*)(sn + 8192 + (wn + nt * 16) * 32 + fbase);     \
    asm volatile("s_waitcnt vmcnt(5)" ::: "memory");                         \
    __builtin_amdgcn_s_barrier();                                            \
    asm volatile("" ::: "memory");                                           \
  }

__global__ __launch_bounds__(512, 2)
void gemm_pv(const f16* __restrict__ Sm, const f16* __restrict__ vt,
             const f16* __restrict__ ics4,
             float* __restrict__ part0, float* __restrict__ part1) {
  __shared__ f16 smem[4 * 16384];
  const int b = blockIdx.x;         // 0..255
  const int sx = b & 7;             // XCD id
  const int q = b >> 3;             // 0..31
  const int bjidx = q & 3;
  const int pr = (q >> 2) * 8 + sx; // pair (split,bi) 0..63; pr&7 == sx
  const int split = pr >> 5;
  const long bi = (long)(pr & 31) * 256;
  const long bj = (long)bjidx * 256;
  const long koff = (long)split * (NPTS / 2);

  const int t = threadIdx.x;
  const int w = t >> 6, l = t & 63;
  const int wm = (w >> 2) * 128, wn = (w & 3) * 64;
  const int lr = l & 15;
  const int fbase = lr * 32 + (((l >> 4) ^ ((lr >> 1) & 3)) * 8);
  const int sro = t >> 2;
  const int scol = ((t & 3) ^ ((t >> 3) & 3)) * 8;
  const f16* gAs = Sm + (bi + sro) * (long)NPTS + koff + scol;
  const f16* gBs = vt + (bj + sro) * (long)NPTS + koff + scol;
  const f16* gic = ics4 + koff + (l >> 4) * 8;   // frag K-chunk for this lane
  const int ldst = w * 512;

  const int nk = (NPTS / 2) / 32;   // 128 K-tiles per split

  f16x8 ic0 = *(const f16x8*)(gic);        // ic(0)
  f16x8 ic1 = *(const f16x8*)(gic + 32);   // ic(1)
#pragma unroll
  for (int tl = 0; tl < 3; ++tl) {
    f16* d = smem + tl * 16384;
    glds16(gAs + tl * 32,               d + ldst);
    glds16(gAs + tl * 32 + 128l * NPTS, d + 4096 + ldst);
    glds16(gBs + tl * 32,               d + 8192 + ldst);
    glds16(gBs + tl * 32 + 128l * NPTS, d + 12288 + ldst);
  }
  asm volatile("s_waitcnt vmcnt(4)" ::: "memory");  // ic0/ic1 + tiles 0,1 landed
  __builtin_amdgcn_s_barrier();
  asm volatile("" ::: "memory");

  f32x4 acc[8][4] = {};
  f16x8 a0[4], b0[4], a1[4], b1[4];
#pragma unroll
  for (int mt = 0; mt < 4; ++mt)
    a0[mt] = *(const f16x8*)(smem + (wm + mt * 16) * 32 + fbase);
#pragma unroll
  for (int nt = 0; nt < 4; ++nt)
    b0[nt] = *(const f16x8*)(smem + 8192 + (wn + nt * 16) * 32 + fbase);

  for (int kt = 0; kt < nk; kt += 2) {
    PV_BODY(kt,     a0, b0, a1, b1, ic0)   // uses ic(kt),   slot0 <- ic(kt+2)
    PV_BODY(kt + 1, a1, b1, a0, b0, ic1)   // uses ic(kt+1), slot1 <- ic(kt+3)
  }

  float* part = split ? part1 : part0;
  const int rbase = (l >> 4) * 4;
#pragma unroll
  for (int mt = 0; mt < 8; ++mt) {
#pragma unroll
    for (int g = 0; g < 4; ++g) {
      const long row = bi + wm + mt * 16 + rbase + g;
      float* Prow = part + row * DIM + bj + wn + lr;
#pragma unroll
      for (int nt = 0; nt < 4; ++nt)
        Prow[nt * 16] = acc[mt][nt][g];
    }
  }
}

extern "C" void kernel_launch(void* const* d_in, const int* in_sizes, int n_in,
                              void* d_out, int out_size, void* d_ws, size_t ws_size,
                              hipStream_t stream) {
  const float* p  = (const float*)d_in[0];
  const float* r  = (const float*)d_in[1];
  const float* Wh = (const float*)d_in[2];
  const float* bh = (const float*)d_in[3];
  const float* Wl = (const float*)d_in[4];
  const float* bl = (const float*)d_in[5];
  const float* Wg = (const float*)d_in[6];
  const float* bg = (const float*)d_in[7];
  float* out = (float*)d_out;

  char* ws = (char*)d_ws;
  f16* q_h  = (f16*)(ws + (0ull  << 20));
  f16* k_h  = (f16*)(ws + (16ull << 20));
  f16* vt_h = (f16*)(ws + (32ull << 20));   // [D,N] v^T, scaled in place
  f16* p_h  = (f16*)(ws + (48ull << 20));
  f16* r_h  = (f16*)(ws + (64ull << 20));
  f16* wh_h = (f16*)(ws + (80ull << 20));
  f16* wl_h = (f16*)(ws + (82ull << 20));
  f16* wg_h = (f16*)(ws + (84ull << 20));
  f16* S    = (f16*)(ws + (96ull << 20));   // 128 MB: exp((s-50)/2) f16
  float* colsum = (float*)(ws + (224ull << 20));
  f16* ics2 = (f16*)(ws + (225ull << 20));
  f16* ics4 = (f16*)(ws + (226ull << 20));
  // PV partials overlay regions dead after QK: q_h/k_h and p_h/r_h (32 MB each)
  float* part0 = (float*)(ws + (0ull  << 20));
  float* part1 = (float*)(ws + (48ull << 20));

  const int nP = NPTS * DIM, nW = DIM * DIM;
  cvt_f32_f16<<<nP / 2048, 256, 0, stream>>>(p,  p_h,  nP);
  cvt_f32_f16<<<nP / 2048, 256, 0, stream>>>(r,  r_h,  nP);
  cvt_f32_f16<<<nW / 2048, 256, 0, stream>>>(Wh, wh_h, nW);
  cvt_f32_f16<<<nW / 2048, 256, 0, stream>>>(Wl, wl_h, nW);
  cvt_f32_f16<<<nW / 2048, 256, 0, stream>>>(Wg, wg_h, nW);
  zero_f32<<<NPTS / 256, 256, 0, stream>>>(colsum, NPTS);

  dim3 blk(256);
  proj_fused<<<1536, blk, 0, stream>>>(p_h, r_h, wh_h, wl_h, wg_h,
                                       bh, bl, bg, q_h, k_h, vt_h);
  gemm_qk<<<1024, dim3(512), 0, stream>>>(q_h, k_h, S, colsum);
  mk_scales<<<NPTS / 256, 256, 0, stream>>>(colsum, ics2, ics4);
  vscale<<<(NPTS / 8) * (DIM / 256), 256, 0, stream>>>(vt_h, ics2);
  gemm_pv<<<256, dim3(512), 0, stream>>>(S, vt_h, ics4, part0, part1);
  reduce_out<<<nP / 1024, 256, 0, stream>>>(p, part0, part1, out);
}